// Round 1
// 450.134 us; speedup vs baseline: 1.0007x; 1.0007x over previous
//
#include <hip/hip_runtime.h>
#include <math.h>

// SpectralConv1d via three GEMMs, bf16 MFMA for the two big ones.
//   Stage 1 (k_dft): Xhat[fh][e] = sum_t TW1[fh][t] * q[t][e], fh<128
//                    rows 0..63 = cos(2pi f t/L) (Xr), rows 64..127 = -sin (Xi).
//                    K=4096 split 4 ways -> fp32 partials Xp[kc][bh][fh][e].
//   Stage 2 (k_mix): reduce partials + complex mode mix with W (fp32),
//                    emit Yhat bf16 pre-shuffled into stage-3 fragment order.
//   Stage 3 (k_inv): out[o][t] = sum_fh Yhat[o][fh] * TW2[fh][t].
//                    OPERAND-SWAPPED: A = TW2 (m=t), B = Yhat (n=o), so the
//                    C fragment holds 4 consecutive t per lane -> dwordx4
//                    nontemporal stores (A/B fragment lane maps are identical,
//                    so the same TW2 table serves as the A operand unchanged).
// Twiddle tables are generated per-launch directly in MFMA fragment order
// (m-or-n = lane&15, k = (lane>>4)*8+j), so operand loads are single coalesced
// b128 global loads (L2/L3-resident) — no LDS in the GEMMs.
//
// ws layout (float units): total 5,242,880 floats = 21 MB.
#define TW1_OFF 0          // bf16[512K]: stage-1 A, frag order [tchunk<128][mt<8][lane][j]
#define TW2_OFF 262144     // bf16[512K]: stage-3 A, frag order [tc<32][nt8<8][ks<4][lane][j]
#define YH_OFF  524288     // bf16[1M] : stage-3 B, frag order [bh][ot<4][ks<4][lane][j]
#define XP_OFF  1048576    // float[4M]: stage-1 partial C [kc<4][bh<128][fh<128][e<64]

typedef short s16x8 __attribute__((ext_vector_type(8)));   // 8 bf16 in 4 VGPRs
typedef float f32x4 __attribute__((ext_vector_type(4)));

__device__ inline unsigned short f2bf(float x) {   // fp32 -> bf16 bits, RNE
    union { float f; unsigned int u; } v; v.f = x;
    return (unsigned short)((v.u + 0x7fffu + ((v.u >> 16) & 1u)) >> 16);
}

// ---------------- twiddle tables, fragment order, bf16 ----------------
__global__ __launch_bounds__(256) void k_tw(float* __restrict__ ws) {
    const int i = blockIdx.x * 256 + threadIdx.x;    // 0..524287
    const float C = 1.53398078788564123e-3f;         // 2*pi/4096
    {   // TW1: fh = mt*16 + (lane&15); t = tch*32 + (lane>>4)*8 + j
        const int j = i & 7, lane = (i >> 3) & 63, mt = (i >> 9) & 7, tch = i >> 12;
        const int fh = mt * 16 + (lane & 15);
        const int t  = tch * 32 + ((lane >> 4) << 3) + j;
        const int f  = fh & 63;
        float s, c;
        sincosf((float)((f * t) & 4095) * C, &s, &c);
        ((unsigned short*)(ws + TW1_OFF))[i] = f2bf(fh < 64 ? c : -s);
    }
    {   // TW2: t = tc*128 + nt*16 + (lane&15); fh = ks*32 + (lane>>4)*8 + j
        const int j = i & 7, lane = (i >> 3) & 63, ks = (i >> 9) & 3, nt = (i >> 11) & 7, tc = i >> 14;
        const int t  = tc * 128 + nt * 16 + (lane & 15);
        const int fh = ks * 32 + ((lane >> 4) << 3) + j;
        const int f  = fh >> 1;
        float s, c;
        sincosf((float)((f * t) & 4095) * C, &s, &c);
        const float sc = (f ? 2.0f : 1.0f) * (1.0f / 4096.0f);
        ((unsigned short*)(ws + TW2_OFF))[i] = f2bf((fh & 1) ? -sc * s : sc * c);
    }
}

// ---------------- stage 1: truncated DFT, bf16 MFMA ----------------
// grid 512 = kc*128 + bh. Block 256 = 4 waves: (wm,wn)=(w>>1,w&1).
// Wave tile M=64 (mt 4) x N=32 (nt 2), K=1024 per block in 64-chunks.
__global__ __launch_bounds__(256) void k_dft(const float* __restrict__ q,
                                             float* __restrict__ ws) {
    const int bid = blockIdx.x;
    const int kc = bid >> 7, bh = bid & 127;
    const int b = bh >> 3, h = bh & 7;
    const int tid = threadIdx.x;
    const int lane = tid & 63, w = tid >> 6;
    const int wm = w >> 1, wn = w & 1;
    const int l15 = lane & 15, qd = lane >> 4;

    const s16x8* __restrict__ tw1 = (const s16x8*)(ws + TW1_OFF);
    const float* __restrict__ qb = q + (size_t)b * 2097152 + h * 64;

    f32x4 acc[4][2];
#pragma unroll
    for (int mt = 0; mt < 4; ++mt)
#pragma unroll
        for (int nt = 0; nt < 2; ++nt)
            acc[mt][nt] = (f32x4){0.f, 0.f, 0.f, 0.f};

    for (int it = 0; it < 16; ++it) {
        const int tch0 = kc * 32 + it * 2;
        s16x8 afr[4][2];
#pragma unroll
        for (int mt = 0; mt < 4; ++mt)
#pragma unroll
            for (int ks = 0; ks < 2; ++ks)
                afr[mt][ks] = tw1[(size_t)((tch0 + ks) * 8 + wm * 4 + mt) * 64 + lane];

        const int tbase = kc * 1024 + it * 64;
        s16x8 bfr[2][2];
#pragma unroll
        for (int nt = 0; nt < 2; ++nt) {
            const int e = wn * 32 + nt * 16 + l15;
#pragma unroll
            for (int ks = 0; ks < 2; ++ks) {
                const float* qp = qb + (size_t)(tbase + ks * 32 + qd * 8) * 512 + e;
#pragma unroll
                for (int j = 0; j < 8; ++j)
                    bfr[nt][ks][j] = (short)f2bf(__builtin_nontemporal_load(qp + (size_t)j * 512));
            }
        }
#pragma unroll
        for (int ks = 0; ks < 2; ++ks)
#pragma unroll
            for (int mt = 0; mt < 4; ++mt)
#pragma unroll
                for (int nt = 0; nt < 2; ++nt)
                    acc[mt][nt] = __builtin_amdgcn_mfma_f32_16x16x32_bf16(
                        afr[mt][ks], bfr[nt][ks], acc[mt][nt], 0, 0, 0);
    }
    // C layout: row m = (lane>>4)*4+reg (verified m89/m91), col n = lane&15.
    float* xp = ws + XP_OFF + (size_t)(kc * 128 + bh) * 8192;
#pragma unroll
    for (int mt = 0; mt < 4; ++mt)
#pragma unroll
        for (int nt = 0; nt < 2; ++nt) {
            const int e = wn * 32 + nt * 16 + l15;
#pragma unroll
            for (int r = 0; r < 4; ++r) {
                const int fh = (wm * 4 + mt) * 16 + qd * 4 + r;
                xp[fh * 64 + e] = acc[mt][nt][r];
            }
        }
}

// ---------------- stage 2: reduce partials + mode mix (fp32) ----------------
// grid 256 = bh*2 + fhalf. Block 512 threads (8 waves -> 2 waves/SIMD).
// Thread: f = f0 + (tid&31), og = tid>>5 (0..15), o = og + 16*oo, oo<4.
__global__ __launch_bounds__(512) void k_mix(const float* __restrict__ wr_g,
                                             const float* __restrict__ wi_g,
                                             float* __restrict__ ws) {
    __shared__ float lds_x[64][69];   // Xr at [e][fl], Xi at [e][fl+34]; 69 breaks banks
    const int bid = blockIdx.x;
    const int bh = bid >> 1, f0 = (bid & 1) * 32;
    const int h = bh & 7;
    const int tid = threadIdx.x;
    const float* xp = ws + XP_OFF;
#pragma unroll
    for (int k2 = 0; k2 < 8; ++k2) {
        const int idx = tid + k2 * 512;          // 0..4095 = 64 rows x 64 e
        const int flp = idx >> 6, e = idx & 63;  // flp 0..63: p = flp>>5, fl = flp&31
        const int p = flp >> 5, fl = flp & 31;
        const int row = p * 64 + f0 + fl;
        float s = 0.f;
#pragma unroll
        for (int kc = 0; kc < 4; ++kc)
            s += xp[(size_t)(kc * 128 + bh) * 8192 + row * 64 + e];
        lds_x[e][fl + p * 34] = s;
    }
    __syncthreads();
    const int fl = tid & 31, og = tid >> 5;
    const int f = f0 + fl;
    float yr[4], yi[4];
#pragma unroll
    for (int oo = 0; oo < 4; ++oo) { yr[oo] = 0.f; yi[oo] = 0.f; }
    const float* wrp = wr_g + (size_t)h * 262144 + og * 64 + f;
    const float* wip = wi_g + (size_t)h * 262144 + og * 64 + f;
    for (int e = 0; e < 64; ++e) {
        const float xr = lds_x[e][fl], xi = lds_x[e][fl + 34];
        const float* wre = wrp + (size_t)e * 4096;
        const float* wie = wip + (size_t)e * 4096;
#pragma unroll
        for (int oo = 0; oo < 4; ++oo) {        // o = og + 16*oo -> stride 1024 floats
            const float wr = wre[oo * 1024];
            const float wi = wie[oo * 1024];
            yr[oo] += xr * wr - xi * wi;
            yi[oo] += xr * wi + xi * wr;
        }
    }
    // scatter-write Yhat in stage-3 B fragment order (n = o&15, k = fh)
    unsigned short* yh = (unsigned short*)(ws + YH_OFF);
#pragma unroll
    for (int oo = 0; oo < 4; ++oo) {
        const int o = og + 16 * oo;
        const int mt = o >> 4, ol = o & 15;
#pragma unroll
        for (int ri = 0; ri < 2; ++ri) {
            const int fh = 2 * f + ri;
            const float v = ri ? yi[oo] : yr[oo];
            yh[((size_t)((bh * 4 + mt) * 4 + (fh >> 5)) * 64 + ((fh >> 3) & 3) * 16 + ol) * 8 + (fh & 7)] = f2bf(v);
        }
    }
}

// ---------------- stage 3: truncated inverse, bf16 MFMA ----------------
// grid 4096 = tc*128 + bh. Wave w: t-range 32 (tt 2 x 16), full o=64 (ot 4),
// K=128 (4 k-steps). A = TW2 (m=t), B = Yhat (n=o): C row = t-local, so each
// lane's f32x4 covers 4 consecutive t -> one dwordx4 nontemporal store each.
__global__ __launch_bounds__(256) void k_inv(float* __restrict__ out,
                                             const float* __restrict__ ws) {
    const int bid = blockIdx.x;
    const int tc = bid >> 7, bh = bid & 127;
    const int tid = threadIdx.x, lane = tid & 63, w = tid >> 6;
    const int l15 = lane & 15, qd = lane >> 4;
    const s16x8* __restrict__ ya = (const s16x8*)(ws + YH_OFF);
    const s16x8* __restrict__ tb = (const s16x8*)(ws + TW2_OFF);
    f32x4 acc[2][4];
#pragma unroll
    for (int tt = 0; tt < 2; ++tt)
#pragma unroll
        for (int ot = 0; ot < 4; ++ot)
            acc[tt][ot] = (f32x4){0.f, 0.f, 0.f, 0.f};
#pragma unroll
    for (int ks = 0; ks < 4; ++ks) {
        s16x8 af[2], bfv[4];
#pragma unroll
        for (int tt = 0; tt < 2; ++tt)          // A: TW2, m = t = tc*128+w*32+tt*16+l15
            af[tt] = tb[(size_t)((tc * 8 + w * 2 + tt) * 4 + ks) * 64 + lane];
#pragma unroll
        for (int ot = 0; ot < 4; ++ot)          // B: Yhat, n = o = ot*16+l15
            bfv[ot] = ya[(size_t)((bh * 4 + ot) * 4 + ks) * 64 + lane];
#pragma unroll
        for (int tt = 0; tt < 2; ++tt)
#pragma unroll
            for (int ot = 0; ot < 4; ++ot)
                acc[tt][ot] = __builtin_amdgcn_mfma_f32_16x16x32_bf16(
                    af[tt], bfv[ot], acc[tt][ot], 0, 0, 0);
    }
    // C layout: row (t-local) = qd*4 + r, col (o-local) = l15.
    float* ob = out + (size_t)bh * 262144 + tc * 128 + w * 32;
#pragma unroll
    for (int tt = 0; tt < 2; ++tt)
#pragma unroll
        for (int ot = 0; ot < 4; ++ot) {
            const int o = ot * 16 + l15;
            float* p = ob + (size_t)o * 4096 + tt * 16 + qd * 4;
            __builtin_nontemporal_store(acc[tt][ot], (f32x4*)p);
        }
}

extern "C" void kernel_launch(void* const* d_in, const int* in_sizes, int n_in,
                              void* d_out, int out_size, void* d_ws, size_t ws_size,
                              hipStream_t stream) {
    const float* q  = (const float*)d_in[0];
    // d_in[1]=k, d_in[2]=v, d_in[3]=mask: unused by the reference forward.
    const float* wr = (const float*)d_in[4];
    const float* wi = (const float*)d_in[5];
    float* out = (float*)d_out;
    float* ws  = (float*)d_ws;    // needs 21 MB

    k_tw <<<2048, 256, 0, stream>>>(ws);
    k_dft<<<512,  256, 0, stream>>>(q, ws);
    k_mix<<<256,  512, 0, stream>>>(wr, wi, ws);
    k_inv<<<4096, 256, 0, stream>>>(out, ws);
}